// Round 6
// baseline (568.329 us; speedup 1.0000x reference)
//
#include <hip/hip_runtime.h>
#include <hip/hip_bf16.h>

// ---------------------------------------------------------------------------
// PCELayer R6 = R5 with conv_mfma v3:
//  - mfma_f32_32x32x16_bf16 (4mt x 2nt per wave), ~13% better MFMA rate,
//    half the MFMA instructions and A-frag reads of v2.
//  - W staged via register prefetch one tap ahead (hides L2 latency behind
//    MFMA of current tap; reg loads don't drain at barriers).
//  - X staged via global_load_lds width=16 (wave-uniform base + lane*16).
// Everything else identical to R5.
// Workspace (153.6 MB):
//   head 16K: wts/stats1/stats2/stats3/statsE
//   wp1T 128K | wp2T 128K
//   XT 16.8M (-> combined_cl after conv) | WT 2.4M
//   YS 134.2M (-> h1cl 67M | h2cl 16.8M | h3 8.4M after combine)
// ---------------------------------------------------------------------------

#define B_ 16
#define CIN_ 128
#define COUT_ 128
#define H_ 64
#define W_ 64
#define HW_ 4096
#define E_ 8
#define FF_ 8
#define GC_ 32
#define HID_ 64
#define HC_ 512

typedef __hip_bfloat16 bf16;
typedef __bf16 bf16x8 __attribute__((ext_vector_type(8)));
typedef float f32x4 __attribute__((ext_vector_type(4)));
typedef float f32x16 __attribute__((ext_vector_type(16)));

__device__ __forceinline__ float siluf(float v) { return v / (1.f + __expf(-v)); }
__device__ __forceinline__ float bf2f(bf16 v) { return __bfloat162float(v); }
__device__ __forceinline__ bf16 f2bf(float v) { return __float2bfloat16(v); }

__device__ __forceinline__ void async_copy16(void* lds, const void* g) {
  __builtin_amdgcn_global_load_lds(
      (const __attribute__((address_space(1))) unsigned int*)g,
      (__attribute__((address_space(3))) unsigned int*)lds, 16, 0, 0);
}

// ---------------- router gate ----------------------------------------------
__global__ void gate_kernel(const float* __restrict__ w1, const float* __restrict__ b1,
                            const float* __restrict__ w2, const float* __restrict__ b2,
                            float* __restrict__ wts) {
  int p = threadIdx.x;
  if (p >= 16) return;
  int i = p >> 2, j = p & 3;
  float cy = (i + 0.5f) * 0.25f;
  float cx = (j + 0.5f) * 0.25f;
  float feats[GC_];
#pragma unroll
  for (int f = 0; f < FF_; ++f) {
    float fr = 3.14159265358979f * (float)(1 << f);
    float ay = cy * fr, ax = cx * fr;
    feats[f] = sinf(ay);
    feats[FF_ + f] = cosf(ay);
    feats[2 * FF_ + f] = sinf(ax);
    feats[3 * FF_ + f] = cosf(ax);
  }
  float hid[HID_];
  for (int k = 0; k < HID_; ++k) {
    float a = b1[k];
#pragma unroll
    for (int m = 0; m < GC_; ++m) a = fmaf(feats[m], w1[m * HID_ + k], a);
    hid[k] = siluf(a);
  }
  float lg[E_];
  float mx = -1e30f;
#pragma unroll
  for (int e = 0; e < E_; ++e) {
    float a = b2[e];
    for (int k = 0; k < HID_; ++k) a = fmaf(hid[k], w2[k * E_ + e], a);
    lg[e] = a;
    mx = fmaxf(mx, a);
  }
  float s = 0.f;
#pragma unroll
  for (int e = 0; e < E_; ++e) { lg[e] = __expf(lg[e] - mx); s += lg[e]; }
  float inv = 1.f / s;
#pragma unroll
  for (int e = 0; e < E_; ++e) wts[p * E_ + e] = lg[e] * inv;
}

// ---------------- x -> channels-last bf16 ----------------------------------
__global__ __launch_bounds__(256) void xt_kernel(const float* __restrict__ x,
                                                 bf16* __restrict__ xT) {
  __shared__ float t[128][65];
  int b = blockIdx.x >> 6, h = blockIdx.x & 63;
  int tid = threadIdx.x;
  int w = tid & 63, c4 = tid >> 6;
  const float* xb = x + ((size_t)(b * 128) * 64 + h) * 64;
#pragma unroll 4
  for (int rep = 0; rep < 32; ++rep) {
    int ci = rep * 4 + c4;
    t[ci][w] = xb[(size_t)ci * HW_ + w];
  }
  __syncthreads();
  bf16* dst = xT + (size_t)(b * 64 + h) * 8192;
#pragma unroll 4
  for (int rep = 0; rep < 32; ++rep) {
    int o = rep * 256 + tid;
    int cg = o >> 9, w2 = (o >> 3) & 63, lo = o & 7;
    dst[o] = f2bf(t[cg * 8 + lo][w2]);
  }
}

// ---------------- w_exp -> wT bf16 -----------------------------------------
__global__ void wt_kernel(const float* __restrict__ w_exp, bf16* __restrict__ wT) {
  int idx = blockIdx.x * 256 + threadIdx.x;
  if (idx >= 1179648) return;
  int lo = idx & 7;
  int co = (idx >> 3) & 127;
  int cg = (idx >> 10) & 15;
  int rest = idx >> 14;
  int tap = rest % 9, e = rest / 9;
  int ci = cg * 8 + lo;
  wT[idx] = f2bf(w_exp[(((size_t)(e * 128 + co) * 128 + ci) * 9) + tap]);
}

// ---------------- pw weights fp32 -> bf16 ----------------------------------
__global__ void wpT_kernel(const float* __restrict__ w_pw1, const float* __restrict__ w_pw2,
                           bf16* __restrict__ wp1T, bf16* __restrict__ wp2T) {
  int idx = blockIdx.x * 256 + threadIdx.x;
  if (idx < 65536) wp1T[idx] = f2bf(w_pw1[idx]);
  else if (idx < 131072) wp2T[idx - 65536] = f2bf(w_pw2[idx - 65536]);
}

// ---------------- expert conv via MFMA (v3: 32x32x16 + prefetch) -----------
// grid: e(8) x b(16) x rt(16 tiles of 4 rows). 256 thr = 4 waves.
// Block: 128co x 256pos. Wave: row h_local=wave, 4mt(32co) x 2nt(32w).
__global__ __launch_bounds__(256, 2) void conv_mfma(
    const bf16* __restrict__ xT, const bf16* __restrict__ wT,
    float* __restrict__ statsE, bf16* __restrict__ ys) {
  __shared__ __align__(16) char xls[8 * 6144];   // [cg(8)][r(6)][w(64)]x16B = 48K
  __shared__ __align__(16) char wls[8 * 2048];   // [cg(8)][co(128)]x16B = 16K
  __shared__ float red[4][8][2];

  int blk = blockIdx.x;
  int rt = blk & 15, b = (blk >> 4) & 15, e = blk >> 8;
  int tid = threadIdx.x, lane = tid & 63, wave = tid >> 6;
  int l31 = lane & 31, lh = lane >> 5;
  int h0 = rt * 4;
  int h_local = wave;

  f32x16 acc[4][2];
#pragma unroll
  for (int mt = 0; mt < 4; ++mt)
#pragma unroll
    for (int nt = 0; nt < 2; ++nt)
#pragma unroll
      for (int r = 0; r < 16; ++r) acc[mt][nt][r] = 0.f;

  bf16x8 bz;
#pragma unroll
  for (int j = 0; j < 8; ++j) bz[j] = (__bf16)0.f;

  uint4 wr[4];
  // W prefetch helper: ht2 = half*9 + tap
  auto wload = [&](int ht2) {
    int half = ht2 / 9, tap = ht2 - half * 9;
#pragma unroll
    for (int s = 0; s < 4; ++s) {
      int seg = wave * 4 + s;
      int cg = seg >> 1, cb = seg & 1;
      wr[s] = *((const uint4*)((const char*)wT +
          ((size_t)(((e * 9 + tap) * 16) + half * 8 + cg) * 128 + cb * 64) * 16) + lane);
    }
  };
  wload(0);

  for (int half = 0; half < 2; ++half) {
    __syncthreads();  // xls readers of previous half done
    // stage X via async DMA: 48 segs of 1KB (cg 8 x r 6), 12 per wave
#pragma unroll
    for (int s = 0; s < 12; ++s) {
      int seg = wave * 12 + s;
      int cg = seg / 6, r = seg % 6;
      int h = h0 - 1 + r;
      char* ldst = xls + cg * 6144 + r * 1024;
      if ((unsigned)h < 64u) {
        const char* g = (const char*)xT +
            ((size_t)((b * 64 + h) * 16) + half * 8 + cg) * 1024 + lane * 16;
        async_copy16(ldst + lane * 16, g);
      } else {
        *(uint4*)(ldst + lane * 16) = make_uint4(0u, 0u, 0u, 0u);
      }
    }
    for (int tap = 0; tap < 9; ++tap) {
      int dr = tap / 3, ds = tap % 3;
      __syncthreads();  // A: wls readers of previous tap done
      // publish prefetched W regs
#pragma unroll
      for (int s = 0; s < 4; ++s) {
        int seg = wave * 4 + s;
        int cg = seg >> 1, cb = seg & 1;
        *(uint4*)(wls + cg * 2048 + cb * 1024 + lane * 16) = wr[s];
      }
      int ht2 = half * 9 + tap + 1;
      if (ht2 < 18) wload(ht2);  // latency hidden behind this tap's MFMA
      __syncthreads();  // B: wls (+ X DMA on first tap) visible
      int r_local = h_local + dr;
#pragma unroll
      for (int kc = 0; kc < 4; ++kc) {
        int cgq = kc * 2 + lh;
        bf16x8 af[4];
#pragma unroll
        for (int mt = 0; mt < 4; ++mt)
          af[mt] = *(const bf16x8*)(wls + cgq * 2048 + (mt * 32 + l31) * 16);
        bf16x8 bfr[2];
#pragma unroll
        for (int nt = 0; nt < 2; ++nt) {
          int w = nt * 32 + l31;
          int wsrc = w + ds - 1;
          bool valid = (unsigned)wsrc < 64u;
          int wc = valid ? wsrc : 0;
          bf16x8 v = *(const bf16x8*)(xls + cgq * 6144 + (r_local * 64 + wc) * 16);
          bfr[nt] = valid ? v : bz;
        }
#pragma unroll
        for (int mt = 0; mt < 4; ++mt)
#pragma unroll
          for (int nt = 0; nt < 2; ++nt)
            acc[mt][nt] = __builtin_amdgcn_mfma_f32_32x32x16_bf16(
                af[mt], bfr[nt], acc[mt][nt], 0, 0, 0);
      }
    }
  }

  // epilogue: raw ys + GN partial stats. C layout: col(n)=lane&31,
  // row = (reg&3) + 8*(reg>>2) + 4*(lane>>5); GN group = 2mt + (reg>>3).
  int hh = h0 + h_local;
  bf16* yb = ys + (size_t)((e * 16 + b) * 128) * 4096;
#pragma unroll
  for (int mt = 0; mt < 4; ++mt) {
    float s[2] = {0.f, 0.f}, ss[2] = {0.f, 0.f};
#pragma unroll
    for (int nt = 0; nt < 2; ++nt) {
      int w = nt * 32 + l31;
      int pos = hh * 64 + w;
#pragma unroll
      for (int reg = 0; reg < 16; ++reg) {
        float v = acc[mt][nt][reg];
        int gi = reg >> 3;
        s[gi] += v;
        ss[gi] += v * v;
        int co = mt * 32 + (reg & 3) + 8 * (reg >> 2) + 4 * lh;
        yb[(size_t)co * 4096 + pos] = f2bf(v);
      }
    }
#pragma unroll
    for (int off = 32; off; off >>= 1) {
      s[0] += __shfl_down(s[0], off, 64);
      ss[0] += __shfl_down(ss[0], off, 64);
      s[1] += __shfl_down(s[1], off, 64);
      ss[1] += __shfl_down(ss[1], off, 64);
    }
    if (lane == 0) {
      red[wave][2 * mt][0] = s[0];
      red[wave][2 * mt][1] = ss[0];
      red[wave][2 * mt + 1][0] = s[1];
      red[wave][2 * mt + 1][1] = ss[1];
    }
  }
  __syncthreads();
  if (tid < 16) {
    int g = tid >> 1, which = tid & 1;
    float t = red[0][g][which] + red[1][g][which] + red[2][g][which] + red[3][g][which];
    atomicAdd(&statsE[((e * 16 + b) * 8 + g) * 2 + which], t);
  }
}

// ---------------- generic stats finalize: raw S/SS -> mean/rstd ------------
__global__ void finalize_stats(float* __restrict__ st, int n, float inv) {
  int i = blockIdx.x * 256 + threadIdx.x;
  if (i >= n) return;
  float S = st[i * 2], SS = st[i * 2 + 1];
  float mean = S * inv;
  float var = SS * inv - mean * mean;
  st[i * 2] = mean;
  st[i * 2 + 1] = rsqrtf(var + 1e-5f);
}

// ---------------- combine -> bf16 channels-last ----------------------------
__global__ __launch_bounds__(256) void combine_cl(
    const float* __restrict__ x, const bf16* __restrict__ ys,
    const float* __restrict__ st, const float* __restrict__ gns,
    const float* __restrict__ gnb, const float* __restrict__ wts,
    bf16* __restrict__ ccl) {
  __shared__ bf16 tile[64][132];
  int b = blockIdx.x >> 6, h = blockIdx.x & 63;
  int t = threadIdx.x;
  int w32 = t & 31, coq = t >> 5;
  float m_[8], r_[8];
#pragma unroll
  for (int e = 0; e < 8; ++e) {
    m_[e] = st[((e * 16 + b) * 8 + coq) * 2];
    r_[e] = st[((e * 16 + b) * 8 + coq) * 2 + 1];
  }
#pragma unroll
  for (int wt2 = 0; wt2 < 2; ++wt2) {
    int w = wt2 * 32 + w32;
    int pid = (h >> 4) * 4 + (w >> 4);
    int pos = h * 64 + w;
    float wt_[8];
#pragma unroll
    for (int e = 0; e < 8; ++e) wt_[e] = wts[pid * 8 + e];
    for (int coi = 0; coi < 16; ++coi) {
      int co = coq * 16 + coi;
      float v = x[((size_t)(b * 128 + co) << 12) + pos];
#pragma unroll
      for (int e = 0; e < 8; ++e) {
        float y = bf2f(ys[((size_t)((e * 16 + b) * 128 + co) << 12) + pos]);
        float yn = (y - m_[e]) * r_[e] * gns[e * 128 + co] + gnb[e * 128 + co];
        v += siluf(yn) * wt_[e];
      }
      tile[w][co] = f2bf(v);
    }
  }
  __syncthreads();
  int row = t >> 2, q = t & 3;
  char* dst = (char*)ccl + ((size_t)(b * 4096 + h * 64 + row)) * 256 + q * 64;
  const char* src = (const char*)&tile[row][0] + q * 64;
#pragma unroll
  for (int i = 0; i < 4; ++i)
    *(uint4*)(dst + i * 16) = *(const uint4*)(src + i * 16);
}

// ---------------- pw1 MFMA: h1[hc=512][n=65536] = w[hc][ci] @ ccl[n][ci] ---
__global__ __launch_bounds__(256) void pw1_mfma(
    const bf16* __restrict__ ccl, const bf16* __restrict__ wp1T,
    bf16* __restrict__ h1cl, float* __restrict__ stats1) {
  __shared__ __align__(16) char ls[65536];  // als 32K | bls 32K ; reused as tile
  __shared__ float red[4][2][2];
  char* als = ls;
  char* bls = ls + 32768;
  int blk = blockIdx.x;
  int ntile = blk & 511, mtile = blk >> 9;
  int n0 = ntile * 128, m0 = mtile * 128;
  int t = threadIdx.x, lane = t & 63, wave = t >> 6;
  int quad = lane >> 4, l15 = lane & 15;
  int b = n0 >> 12;

#pragma unroll
  for (int i = 0; i < 8; ++i) {
    int id = t + 256 * i;
    int r = id >> 4, c = id & 15;
    *(uint4*)(als + c * 2048 + r * 16) =
        *(const uint4*)((const char*)wp1T + (size_t)(m0 + r) * 256 + c * 16);
    *(uint4*)(bls + c * 2048 + r * 16) =
        *(const uint4*)((const char*)ccl + (size_t)(n0 + r) * 256 + c * 16);
  }
  __syncthreads();

  f32x4 acc[8][2];
#pragma unroll
  for (int mt = 0; mt < 8; ++mt)
#pragma unroll
    for (int nt = 0; nt < 2; ++nt) acc[mt][nt] = (f32x4){0.f, 0.f, 0.f, 0.f};

#pragma unroll
  for (int kc = 0; kc < 4; ++kc) {
    int cgq = kc * 4 + quad;
    bf16x8 af[8];
#pragma unroll
    for (int mt = 0; mt < 8; ++mt)
      af[mt] = *(const bf16x8*)(als + cgq * 2048 + (mt * 16 + l15) * 16);
    bf16x8 bfr[2];
#pragma unroll
    for (int nt = 0; nt < 2; ++nt)
      bfr[nt] = *(const bf16x8*)(bls + cgq * 2048 + (wave * 32 + nt * 16 + l15) * 16);
#pragma unroll
    for (int mt = 0; mt < 8; ++mt)
#pragma unroll
      for (int nt = 0; nt < 2; ++nt)
        acc[mt][nt] = __builtin_amdgcn_mfma_f32_16x16x32_bf16(
            af[mt], bfr[nt], acc[mt][nt], 0, 0, 0);
  }

  __syncthreads();  // everyone done with als/bls
  float s[2] = {0.f, 0.f}, ss[2] = {0.f, 0.f};
  bf16* tile = (bf16*)ls;  // row stride 132 elems = 264 B
#pragma unroll
  for (int mt = 0; mt < 8; ++mt) {
    int gi = mt >> 2;
#pragma unroll
    for (int nt = 0; nt < 2; ++nt) {
      int n = wave * 32 + nt * 16 + l15;
#pragma unroll
      for (int r = 0; r < 4; ++r) {
        float v = acc[mt][nt][r];
        s[gi] += v;
        ss[gi] += v * v;
        tile[n * 132 + mt * 16 + quad * 4 + r] = f2bf(v);
      }
    }
  }
#pragma unroll
  for (int gi = 0; gi < 2; ++gi) {
#pragma unroll
    for (int off = 32; off; off >>= 1) {
      s[gi] += __shfl_down(s[gi], off, 64);
      ss[gi] += __shfl_down(ss[gi], off, 64);
    }
  }
  if (lane == 0) {
    red[wave][0][0] = s[0]; red[wave][0][1] = ss[0];
    red[wave][1][0] = s[1]; red[wave][1][1] = ss[1];
  }
  __syncthreads();
  if (t < 4) {
    int gi = t >> 1, which = t & 1;
    float v = red[0][gi][which] + red[1][gi][which] + red[2][gi][which] + red[3][gi][which];
    atomicAdd(&stats1[(b * 8 + mtile * 2 + gi) * 2 + which], v);
  }
#pragma unroll
  for (int i = 0; i < 8; ++i) {
    int id = t + 256 * i;             // 0..2047
    int r = id >> 4, q = id & 15;     // 128 rows x 16 chunks of 16B
    char* dst = (char*)h1cl + (size_t)(n0 + r) * 1024 + m0 * 2 + q * 16;
    const char* src = (const char*)tile + r * 264 + q * 16;
    *(uint4*)dst = *(const uint4*)src;
  }
}

// ---------------- dw3x3 v2: LDS-staged GN1+SiLU tile + sliding stencil -----
__global__ __launch_bounds__(256) void dw_cl(
    const bf16* __restrict__ h1cl, const float* __restrict__ w_dw,
    const float* __restrict__ st1, const float* __restrict__ gs,
    const float* __restrict__ gb, bf16* __restrict__ h2cl,
    float* __restrict__ stats2) {
  __shared__ __align__(16) bf16 tile[18 * 66 * 16];  // 38016 B
  __shared__ float red2[4][2];
  int blk = blockIdx.x;
  int ht = blk & 3, hcg = (blk >> 2) & 31, b = blk >> 7;
  int h0 = ht * 16;
  int hc0 = hcg * 16;
  int hcb = hcg >> 2;  // 64-hc GN group
  int t = threadIdx.x;

  float mean = st1[(b * 8 + hcb) * 2], rstd = st1[(b * 8 + hcb) * 2 + 1];
  float scale[16], shift[16];
#pragma unroll
  for (int j = 0; j < 16; ++j) {
    float g = gs[hc0 + j];
    scale[j] = rstd * g;
    shift[j] = gb[hc0 + j] - mean * rstd * g;
  }

  for (int i = 0; i < 5; ++i) {
    int idx = t + 256 * i;
    if (idx >= 1188) break;
    int row = idx / 66, wslot = idx - row * 66;
    int hh = h0 - 1 + row;
    int w = wslot - 1;
    int swz = (wslot >> 2) & 3;
    bf16* dst = tile + (row * 66 + wslot) * 16;
    if ((unsigned)hh < 64u && (unsigned)w < 64u) {
      const char* p = (const char*)h1cl + ((size_t)(b * 4096 + hh * 64 + w) * 512 + hc0) * 2;
      uint4 a0 = *(const uint4*)p;
      uint4 a1 = *(const uint4*)(p + 16);
      const bf16* pv = (const bf16*)&a0;
      const bf16* pv1 = (const bf16*)&a1;
      bf16 outv[16];
#pragma unroll
      for (int j = 0; j < 8; ++j)
        outv[j] = f2bf(siluf(bf2f(pv[j]) * scale[j] + shift[j]));
#pragma unroll
      for (int j = 0; j < 8; ++j)
        outv[8 + j] = f2bf(siluf(bf2f(pv1[j]) * scale[8 + j] + shift[8 + j]));
#pragma unroll
      for (int qq = 0; qq < 4; ++qq) {
        int ph = (qq + swz) & 3;
        *(uint2*)(dst + ph * 4) = *(const uint2*)(outv + qq * 4);
      }
    } else {
      *(uint4*)dst = make_uint4(0u, 0u, 0u, 0u);
      *(uint4*)(dst + 8) = make_uint4(0u, 0u, 0u, 0u);
    }
  }
  __syncthreads();

  int w = t & 63, q = t >> 6;
  float wv[9][4];
#pragma unroll
  for (int j = 0; j < 4; ++j) {
    int hc = hc0 + q * 4 + j;
#pragma unroll
    for (int tap = 0; tap < 9; ++tap) wv[tap][j] = w_dw[hc * 9 + tap];
  }

  f32x4 win[3][3];
  float acc_s = 0.f, acc_ss = 0.f;

  auto ld4 = [&](int r, int dwi) -> f32x4 {
    int slot = w + dwi;
    int ph = (q + (slot >> 2)) & 3;
    const bf16* p = tile + (r * 66 + slot) * 16 + ph * 4;
    uint2 u = *(const uint2*)p;
    const bf16* pb = (const bf16*)&u;
    return (f32x4){bf2f(pb[0]), bf2f(pb[1]), bf2f(pb[2]), bf2f(pb[3])};
  };

#pragma unroll
  for (int dwi = 0; dwi < 3; ++dwi) {
    win[0][dwi] = ld4(0, dwi);
    win[1][dwi] = ld4(1, dwi);
  }
#pragma unroll
  for (int orow = 0; orow < 16; ++orow) {
    int rnew = orow + 2;
    int ringn = rnew % 3;
#pragma unroll
    for (int dwi = 0; dwi < 3; ++dwi) win[ringn][dwi] = ld4(rnew, dwi);
    f32x4 acc = (f32x4){0.f, 0.f, 0.f, 0.f};
#pragma unroll
    for (int dr = 0; dr < 3; ++dr) {
      int ring = (orow + dr) % 3;
#pragma unroll
      for (int dwi = 0; dwi < 3; ++dwi) {
#pragma unroll
        for (int j = 0; j < 4; ++j)
          acc[j] = fmaf(win[ring][dwi][j], wv[dr * 3 + dwi][j], acc[j]);
      }
    }
#pragma unroll
    for (int j = 0; j < 4; ++j) { acc_s += acc[j]; acc_ss += acc[j] * acc[j]; }
    if (!(orow & 1) && !(w & 1)) {
      int hglob = h0 + orow;
      int pos2 = (hglob >> 1) * 32 + (w >> 1);
      bf16 tmp[4];
#pragma unroll
      for (int j = 0; j < 4; ++j) tmp[j] = f2bf(acc[j]);
      *(uint2*)((char*)h2cl + ((size_t)(b * 1024 + pos2) * 512 + hc0 + q * 4) * 2) =
          *(const uint2*)tmp;
    }
  }

#pragma unroll
  for (int off = 32; off; off >>= 1) {
    acc_s += __shfl_down(acc_s, off, 64);
    acc_ss += __shfl_down(acc_ss, off, 64);
  }
  int wave = t >> 6;
  if ((t & 63) == 0) { red2[wave][0] = acc_s; red2[wave][1] = acc_ss; }
  __syncthreads();
  if (t < 2) {
    float v = red2[0][t] + red2[1][t] + red2[2][t] + red2[3][t];
    atomicAdd(&stats2[(b * 8 + hcb) * 2 + t], v);
  }
}

// ---------------- norm2 in-place on compact h2cl ---------------------------
__global__ void norm2_kernel(bf16* __restrict__ h2, const float* __restrict__ st2,
                             const float* __restrict__ gs, const float* __restrict__ gb) {
  int tg = blockIdx.x * 256 + threadIdx.x;
  int e8 = tg * 8;
  int hc0 = e8 & 511;
  int rest = e8 >> 9;
  int bq = rest >> 10;
  int g = hc0 >> 6;
  float mean = st2[(bq * 8 + g) * 2], rstd = st2[(bq * 8 + g) * 2 + 1];
  uint4 v = *(const uint4*)((const char*)h2 + (size_t)tg * 16);
  bf16* pv = (bf16*)&v;
  bf16 outv[8];
#pragma unroll
  for (int j = 0; j < 8; ++j) {
    float x = bf2f(pv[j]);
    x = (x - mean) * rstd * gs[hc0 + j] + gb[hc0 + j];
    outv[j] = f2bf(siluf(x));
  }
  *(uint4*)((char*)h2 + (size_t)tg * 16) = *(const uint4*)outv;
}

// ---------------- pw2 MFMA: h3[co=128][n=16384] = w[co][hc] @ h2n[n][hc] ---
__global__ __launch_bounds__(256) void pw2_mfma(
    const bf16* __restrict__ h2n, const bf16* __restrict__ wp2T,
    float* __restrict__ h3, float* __restrict__ stats3) {
  __shared__ __align__(16) char als[2][8192];
  __shared__ __align__(16) char bls[2][4096];
  __shared__ float red[4][8][2];
  int blk = blockIdx.x;
  int n0 = blk * 64;
  int b = n0 >> 10, posb = n0 & 1023;
  int t = threadIdx.x, lane = t & 63, wave = t >> 6;
  int quad = lane >> 4, l15 = lane & 15;
  int wbase = wave * 16;

  f32x4 acc[8];
#pragma unroll
  for (int mt = 0; mt < 8; ++mt) acc[mt] = (f32x4){0.f, 0.f, 0.f, 0.f};

  {
#pragma unroll
    for (int i = 0; i < 2; ++i) {
      int id = t + 256 * i;
      int c4 = id >> 7, r = id & 127;
      *(uint4*)(als[0] + c4 * 2048 + r * 16) =
          *(const uint4*)((const char*)wp2T + (size_t)r * 1024 + c4 * 16);
    }
    int c4 = t >> 6, r = t & 63;
    *(uint4*)(bls[0] + c4 * 1024 + r * 16) =
        *(const uint4*)((const char*)h2n + (size_t)(n0 + r) * 1024 + c4 * 16);
  }
  for (int kc = 0; kc < 16; ++kc) {
    __syncthreads();
    if (kc + 1 < 16) {
      int nb = (kc + 1) & 1;
#pragma unroll
      for (int i = 0; i < 2; ++i) {
        int id = t + 256 * i;
        int c4 = id >> 7, r = id & 127;
        *(uint4*)(als[nb] + c4 * 2048 + r * 16) =
            *(const uint4*)((const char*)wp2T + (size_t)r * 1024 + ((kc + 1) * 4 + c4) * 16);
      }
      int c4 = t >> 6, r = t & 63;
      *(uint4*)(bls[nb] + c4 * 1024 + r * 16) =
          *(const uint4*)((const char*)h2n + (size_t)(n0 + r) * 1024 + ((kc + 1) * 4 + c4) * 16);
    }
    int buf = kc & 1;
    bf16x8 bf1 = *(const bf16x8*)(bls[buf] + quad * 1024 + (wbase + l15) * 16);
#pragma unroll
    for (int mt = 0; mt < 8; ++mt) {
      bf16x8 af = *(const bf16x8*)(als[buf] + quad * 2048 + (mt * 16 + l15) * 16);
      acc[mt] = __builtin_amdgcn_mfma_f32_16x16x32_bf16(af, bf1, acc[mt], 0, 0, 0);
    }
  }

#pragma unroll
  for (int mt = 0; mt < 8; ++mt) {
    float s = 0.f, ss = 0.f;
    int pos = posb + wbase + l15;
#pragma unroll
    for (int r = 0; r < 4; ++r) {
      float v = acc[mt][r];
      s += v;
      ss += v * v;
      int co = mt * 16 + quad * 4 + r;
      h3[(size_t)(b * 128 + co) * 1024 + pos] = v;
    }
#pragma unroll
    for (int off = 32; off; off >>= 1) {
      s += __shfl_down(s, off, 64);
      ss += __shfl_down(ss, off, 64);
    }
    if (lane == 0) { red[wave][mt][0] = s; red[wave][mt][1] = ss; }
  }
  __syncthreads();
  if (t < 16) {
    int mt = t >> 1, which = t & 1;
    float v = red[0][mt][which] + red[1][mt][which] + red[2][mt][which] + red[3][mt][which];
    atomicAdd(&stats3[(b * 8 + mt) * 2 + which], v);
  }
}

// ---------------- final GN+SiLU -> d_out (fp32) ----------------------------
__global__ void out_kernel(const float* __restrict__ h3, const float* __restrict__ stats,
                           const float* __restrict__ gs, const float* __restrict__ gb,
                           float* __restrict__ out) {
  const int total = B_ * COUT_ * 1024;
  for (int idx = blockIdx.x * blockDim.x + threadIdx.x; idx < total; idx += gridDim.x * blockDim.x) {
    int c = (idx >> 10) & 127;
    int b = idx >> 17;
    int bg = b * 8 + (c >> 4);
    float S = stats[bg * 2], SS = stats[bg * 2 + 1];
    float mean = S * (1.f / 16384.f);
    float var = SS * (1.f / 16384.f) - mean * mean;
    float rstd = rsqrtf(var + 1e-5f);
    float v = (h3[idx] - mean) * rstd * gs[c] + gb[c];
    out[idx] = siluf(v);
  }
}

extern "C" void kernel_launch(void* const* d_in, const int* in_sizes, int n_in,
                              void* d_out, int out_size, void* d_ws, size_t ws_size,
                              hipStream_t stream) {
  const float* x = (const float*)d_in[0];
  const float* w_exp = (const float*)d_in[1];
  const float* gn_exp_s = (const float*)d_in[2];
  const float* gn_exp_b = (const float*)d_in[3];
  const float* w1 = (const float*)d_in[4];
  const float* b1 = (const float*)d_in[5];
  const float* w2 = (const float*)d_in[6];
  const float* b2 = (const float*)d_in[7];
  const float* w_pw1 = (const float*)d_in[8];
  const float* gn1_s = (const float*)d_in[9];
  const float* gn1_b = (const float*)d_in[10];
  const float* w_dw = (const float*)d_in[11];
  const float* gn2_s = (const float*)d_in[12];
  const float* gn2_b = (const float*)d_in[13];
  const float* w_pw2 = (const float*)d_in[14];
  const float* gn3_s = (const float*)d_in[15];
  const float* gn3_b = (const float*)d_in[16];

  char* ws = (char*)d_ws;
  const size_t WP1T_OFF = 16384;
  const size_t WP2T_OFF = WP1T_OFF + 131072;
  const size_t XT_OFF = WP2T_OFF + 131072;                 // 278528
  const size_t WT_OFF = XT_OFF + 16777216;                 // 17055744
  const size_t YS_OFF = WT_OFF + 2359296;                  // 19415040
  const size_t NEEDED = YS_OFF + 134217728;                // 153632768
  if (ws_size < NEEDED) return;

  float* wts = (float*)ws;
  float* stats1 = (float*)(ws + 1024);
  float* stats2 = (float*)(ws + 2048);
  float* stats3 = (float*)(ws + 3072);
  float* statsE = (float*)(ws + 4096);
  bf16* wp1T = (bf16*)(ws + WP1T_OFF);
  bf16* wp2T = (bf16*)(ws + WP2T_OFF);
  bf16* xT = (bf16*)(ws + XT_OFF);
  bf16* ccl = (bf16*)(ws + XT_OFF);
  bf16* wT = (bf16*)(ws + WT_OFF);
  bf16* ys = (bf16*)(ws + YS_OFF);
  bf16* h1cl = (bf16*)(ws + YS_OFF);
  bf16* h2cl = (bf16*)(ws + YS_OFF + 67108864);
  float* h3 = (float*)(ws + YS_OFF + 83886080);

  hipMemsetAsync(ws, 0, 16384, stream);
  gate_kernel<<<1, 64, 0, stream>>>(w1, b1, w2, b2, wts);
  xt_kernel<<<B_ * 64, 256, 0, stream>>>(x, xT);
  wt_kernel<<<4608, 256, 0, stream>>>(w_exp, wT);
  wpT_kernel<<<512, 256, 0, stream>>>(w_pw1, w_pw2, wp1T, wp2T);
  conv_mfma<<<E_ * B_ * 16, 256, 0, stream>>>(xT, wT, statsE, ys);
  finalize_stats<<<4, 256, 0, stream>>>(statsE, 1024, 1.f / 65536.f);
  combine_cl<<<B_ * 64, 256, 0, stream>>>(x, ys, statsE, gn_exp_s, gn_exp_b, wts, ccl);
  pw1_mfma<<<4 * 512, 256, 0, stream>>>(ccl, wp1T, h1cl, stats1);
  finalize_stats<<<1, 128, 0, stream>>>(stats1, 128, 1.f / 262144.f);
  dw_cl<<<B_ * 32 * 4, 256, 0, stream>>>(h1cl, w_dw, stats1, gn1_s, gn1_b, h2cl, stats2);
  finalize_stats<<<1, 128, 0, stream>>>(stats2, 128, 1.f / 262144.f);
  norm2_kernel<<<4096, 256, 0, stream>>>(h2cl, stats2, gn2_s, gn2_b);
  pw2_mfma<<<256, 256, 0, stream>>>(h2cl, wp2T, h3, stats3);
  out_kernel<<<1024, 256, 0, stream>>>(h3, stats3, gn3_s, gn3_b, (float*)d_out);
}